// Round 9
// baseline (516.723 us; speedup 1.0000x reference)
//
#include <hip/hip_runtime.h>
#include <hip/hip_bf16.h>

// AdditiveAttention on MI355X (gfx950)
// B=64, S=2048, D=512, U=512. All inputs fp32; output fp32 (B,D).
//
// R11: async-DMA staging. 7 rounds established: phases fully serialize and
// register-resident prefetch is always sunk by the allocator (R4/R6/R10).
// global_load_lds has NO register result -> cannot be sunk: issue DMA for
// chunk c+1, compute chunk c, __syncthreads (drains vmcnt). A staged as RAW
// fp32 (DMA can't convert); fp32->bf16 happens at ds_read time via cvt_pk.
// Swizzle via pre-swizzled per-lane GLOBAL source addresses (LDS dest is
// linear, guide m173); read-side XOR unchanged (2-way conflicts, free).
// Geometry = R8: 8 waves, wave owns 4 ntiles (c_w=64), acc[4][4].
// K-chunks of 128: LDS 2 x 32KB fp32 dbuf -> 2 blocks/CU.

typedef __attribute__((ext_vector_type(8))) short bf16x8;
typedef __attribute__((ext_vector_type(4))) float f32x4;

#define GLOBAL_AS __attribute__((address_space(1)))
#define LDS_AS __attribute__((address_space(3)))

#if __has_builtin(__builtin_amdgcn_exp2f)
__device__ __forceinline__ float fast_exp2(float x) { return __builtin_amdgcn_exp2f(x); }
#else
__device__ __forceinline__ float fast_exp2(float x) { return exp2f(x); }
#endif
#if __has_builtin(__builtin_amdgcn_rcpf)
__device__ __forceinline__ float fast_rcp(float x) { return __builtin_amdgcn_rcpf(x); }
#else
__device__ __forceinline__ float fast_rcp(float x) { return 1.0f / x; }
#endif

__device__ __forceinline__ unsigned short f2bf(float f) {
  unsigned int u = __float_as_uint(f);
  u += 0x7fffu + ((u >> 16) & 1u);
  return (unsigned short)(u >> 16);
}

// pack two fp32 -> one dword of 2 bf16 (lo = a, hi = b), RNE via HIP intrinsics
__device__ __forceinline__ unsigned int cvt_pk_bf16(float a, float b) {
  const __hip_bfloat16 lo = __float2bfloat16(a);
  const __hip_bfloat16 hi = __float2bfloat16(b);
  const unsigned short ul = *reinterpret_cast<const unsigned short*>(&lo);
  const unsigned short uh = *reinterpret_cast<const unsigned short*>(&hi);
  return (unsigned int)ul | ((unsigned int)uh << 16);
}

// ---------------- k1: fused prep = qk (blocks 0..127) + wt_k (128..255) -----
// qk: Q = query @ W1, 64x2 sub-blocks x 256 thr.
// wt: Wtf fragment-ordered bf16(W2^T):
// Wtf[((ntile*16+ks)*64 + quad*16 + l15)*8 + j] = bf16(W2[ks*32+quad*8+j][ntile*16+l15])
__global__ __launch_bounds__(256) void prep_k(
    const float* __restrict__ query, const float* __restrict__ W1,
    const float* __restrict__ W2, float* __restrict__ Q,
    unsigned short* __restrict__ Wtf) {
  __shared__ float qrow[512];
  const int t = threadIdx.x;
  if (blockIdx.x < 128) {
    const int b = blockIdx.x >> 1, half = blockIdx.x & 1;
    qrow[t] = query[b * 512 + t];
    qrow[t + 256] = query[b * 512 + t + 256];
    __syncthreads();
    const int u = half * 256 + t;
    float acc = 0.f;
#pragma unroll 8
    for (int k = 0; k < 512; ++k) acc += qrow[k] * W1[(size_t)k * 512 + u];
    Q[b * 512 + u] = acc;
  } else {
    const int gid = (blockIdx.x - 128) * 256 + t;  // 0..32767
    const int lane = gid & 63;
    const int g = gid >> 6;  // ntile*16 + ks
    const int ks = g & 15, ntile = g >> 4;
    const int l15 = lane & 15, quad = lane >> 4;
    const int n = ntile * 16 + l15;
    const int k0 = ks * 32 + quad * 8;
    unsigned int p[4];
#pragma unroll
    for (int jj = 0; jj < 4; ++jj) {
      const float a = W2[(size_t)(k0 + 2 * jj) * 512 + n];
      const float b = W2[(size_t)(k0 + 2 * jj + 1) * 512 + n];
      p[jj] = (unsigned int)f2bf(a) | ((unsigned int)f2bf(b) << 16);
    }
    *(uint4*)&Wtf[(size_t)gid * 8] = make_uint4(p[0], p[1], p[2], p[3]);
  }
}

// ---------------- k2: fused scores + split-softmax partial context ----------
// Block: 64 rows x full U=512, K=512. 8 waves; wave w owns n-tiles w*4..w*4+3.
// A: fp32, DMA'd per 128-k chunk via global_load_lds (16B/lane), 2x32KB dbuf.
//   LDS layout: row r at byte r*512; 16B slot s holds global 16B-chunk
//   kc = s ^ (r&7) of the current k-chunk (pre-swizzled source addresses).
// B fragments: contiguous 1KB wave loads from fragment-ordered Wtf (L2-res).
// Epilogue: tanh+V1 reduce -> sAcc -> local softmax -> partial ctx.
__global__ __launch_bounds__(512, 4) void scorectx_k(
    const float* __restrict__ values, const unsigned short* __restrict__ Wtf,
    const float* __restrict__ Q, const float* __restrict__ V1,
    float* __restrict__ Pstat, float* __restrict__ Pctx) {
  __shared__ __align__(16) float Ab[2][64 * 128];  // 2 x 32KB fp32
  __shared__ float sAcc[64];
  __shared__ float wLDS[64];

  const int t = threadIdx.x;
  const int lane = t & 63;
  const int w = t >> 6;        // wave 0..7
  const int quad = lane >> 4;  // 0..3
  const int l15 = lane & 15;
  const int blk = blockIdx.x;
  const int m0 = blk * 64;
  const int b = m0 >> 11;  // /2048

  if (t < 64) sAcc[t] = 0.0f;

  // ---- DMA stage geometry: per wave 4 calls; call j covers rows
  // r0 = (w*4+j)*2, r0+1 (64 lanes x 16B = 1KB). lane l: row r = r0+(l>>5),
  // slot s = l&31; source chunk kc = s ^ (r&7)  (involution => read-XOR same).
  const int srow = (lane >> 5);       // 0..1
  const int sslot = lane & 31;        // 16B slot in row
  const float* vbase = values + (size_t)m0 * 512;

#define STAGE_CHUNK(buf, c)                                                          \
  {                                                                                  \
    _Pragma("unroll") for (int j = 0; j < 4; ++j) {                                  \
      const int r = (w * 4 + j) * 2 + srow;                                          \
      const int kc = sslot ^ (r & 7);                                                \
      const float* gsrc = vbase + (size_t)r * 512 + (c) * 128 + kc * 4;              \
      LDS_AS unsigned int* ldst =                                                    \
          (LDS_AS unsigned int*)&Ab[buf][(w * 4 + j) * 256];                         \
      __builtin_amdgcn_global_load_lds((const GLOBAL_AS unsigned int*)gsrc, ldst,    \
                                       16, 0, 0);                                    \
    }                                                                                \
  }

  // ---- prologue: stage chunk 0 into buf 0
  STAGE_CHUNK(0, 0)
  __syncthreads();

  f32x4 acc[4][4];
#pragma unroll
  for (int mt = 0; mt < 4; ++mt)
#pragma unroll
    for (int nt = 0; nt < 4; ++nt) acc[mt][nt] = (f32x4){0.f, 0.f, 0.f, 0.f};

  const unsigned short* Bg = Wtf + (size_t)lane * 8;  // + ((ntile*16+ks)*512)
  const int sw = l15 & 7;  // read swizzle key (m&7 == l15&7)

#pragma unroll
  for (int c = 0; c < 4; ++c) {  // 4 k-chunks of 128
    if (c < 3) STAGE_CHUNK((c + 1) & 1, c + 1)  // DMA flies under compute

    const float* Ac = &Ab[c & 1][0];
#pragma unroll
    for (int kl = 0; kl < 4; ++kl) {  // 4 k-steps of 32 within chunk
      const int ks = c * 4 + kl;
      bf16x8 bfr[4], af[4];
#pragma unroll
      for (int nt = 0; nt < 4; ++nt)
        bfr[nt] = *(const bf16x8*)(Bg + (size_t)((w * 4 + nt) * 16 + ks) * 512);
#pragma unroll
      for (int mt = 0; mt < 4; ++mt) {
        const int m = mt * 16 + l15;
        const int kc0 = kl * 8 + quad * 2;  // even
        const int s0 = kc0 ^ sw;
        const f32x4 f0 = *(const f32x4*)&Ac[m * 128 + ((s0) << 2)];
        const f32x4 f1 = *(const f32x4*)&Ac[m * 128 + ((s0 ^ 1) << 2)];
        union {
          unsigned int d[4];
          bf16x8 v;
        } u;
        u.d[0] = cvt_pk_bf16(f0[0], f0[1]);
        u.d[1] = cvt_pk_bf16(f0[2], f0[3]);
        u.d[2] = cvt_pk_bf16(f1[0], f1[1]);
        u.d[3] = cvt_pk_bf16(f1[2], f1[3]);
        af[mt] = u.v;
      }
#pragma unroll
      for (int mt = 0; mt < 4; ++mt)
#pragma unroll
        for (int nt = 0; nt < 4; ++nt)
          acc[mt][nt] = __builtin_amdgcn_mfma_f32_16x16x32_bf16(af[mt], bfr[nt],
                                                                acc[mt][nt], 0, 0, 0);
    }
    __syncthreads();  // drains DMA (vmcnt) + LDS reads before buffer swap
  }

  // ---- epilogue: part[m] += tanh(acc + Q[b,n]) * V1[n], reduce over n
  // C/D layout: col(n) = lane&15, row(m within tile) = quad*4 + r
  float part[4][4];
#pragma unroll
  for (int mt = 0; mt < 4; ++mt)
#pragma unroll
    for (int r = 0; r < 4; ++r) part[mt][r] = 0.f;

#pragma unroll
  for (int nt = 0; nt < 4; ++nt) {
    const int n = w * 64 + nt * 16 + l15;
    const float qv = Q[b * 512 + n];
    const float v1 = V1[n];
#pragma unroll
    for (int mt = 0; mt < 4; ++mt)
#pragma unroll
      for (int r = 0; r < 4; ++r) {
        const float x = acc[mt][nt][r] + qv;
        const float e = fast_exp2(x * 2.8853900817779268f);  // e^{2x}
        const float th = 1.0f - 2.0f * fast_rcp(e + 1.0f);   // tanh(x)
        part[mt][r] += th * v1;
      }
  }
#pragma unroll
  for (int mt = 0; mt < 4; ++mt)
#pragma unroll
    for (int r = 0; r < 4; ++r) {
      float v = part[mt][r];
      v += __shfl_xor(v, 1);
      v += __shfl_xor(v, 2);
      v += __shfl_xor(v, 4);
      v += __shfl_xor(v, 8);
      if (l15 == 0) atomicAdd(&sAcc[mt * 16 + quad * 4 + r], v);
    }
  __syncthreads();

  // ---- local softmax partials (wave 0: lanes 0..63 own the 64 rows)
  const float L2E = 1.4426950408889634f;
  if (t < 64) {
    const float v = sAcc[t];
    float m = v;
#pragma unroll
    for (int o = 1; o < 64; o <<= 1) m = fmaxf(m, __shfl_xor(m, o));
    const float wv = fast_exp2((v - m) * L2E);
    float dsum = wv;
#pragma unroll
    for (int o = 1; o < 64; o <<= 1) dsum += __shfl_xor(dsum, o);
    wLDS[t] = wv;
    if (t == 0) {
      Pstat[2 * blk] = m;
      Pstat[2 * blk + 1] = dsum;
    }
  }
  __syncthreads();

  // ---- partial context: thread t owns column u=t over the block's 64 rows.
  // fp32 re-read from global (rows just streamed -> mostly L2-hit).
  const float* vrow = values + (size_t)m0 * 512 + t;
  float cacc = 0.f;
#pragma unroll 8
  for (int r = 0; r < 64; ++r) cacc += wLDS[r] * vrow[(size_t)r * 512];
  Pctx[(size_t)blk * 512 + t] = cacc;
#undef STAGE_CHUNK
}

// ---------------- k3: combine partials ------------------------------------
// grid 64 (one per b) x 512 thr. 32 partials per b: global max M, denom
// D = sum d_i*exp(m_i-M); out[b,d] = sum_i ctx_i[d]*exp(m_i-M) / D. 4MB read.
__global__ __launch_bounds__(512) void comb_k(const float* __restrict__ Pstat,
                                              const float* __restrict__ Pctx,
                                              float* __restrict__ out) {
  __shared__ float aL[32];
  __shared__ float Dsh;
  const int b = blockIdx.x, t = threadIdx.x;
  const float L2E = 1.4426950408889634f;
  if (t < 32) {
    const float2 st = ((const float2*)Pstat)[b * 32 + t];
    float m = st.x;
#pragma unroll
    for (int o = 1; o < 32; o <<= 1) m = fmaxf(m, __shfl_xor(m, o));
    const float a = fast_exp2((st.x - m) * L2E);
    float D = a * st.y;
#pragma unroll
    for (int o = 1; o < 32; o <<= 1) D += __shfl_xor(D, o);
    aL[t] = a;
    if (t == 0) Dsh = D;
  }
  __syncthreads();
  const float* pc = Pctx + (size_t)b * 32 * 512 + t;
  float acc = 0.f;
#pragma unroll
  for (int i = 0; i < 32; ++i) acc += aL[i] * pc[(size_t)i * 512];
  out[b * 512 + t] = acc / Dsh;
}

extern "C" void kernel_launch(void* const* d_in, const int* in_sizes, int n_in,
                              void* d_out, int out_size, void* d_ws, size_t ws_size,
                              hipStream_t stream) {
  const float* query = (const float*)d_in[0];   // (64, 512)
  const float* values = (const float*)d_in[1];  // (64, 2048, 512)
  const float* W1 = (const float*)d_in[2];      // (512, 512)
  const float* W2 = (const float*)d_in[3];      // (512, 512)
  const float* V1 = (const float*)d_in[4];      // (512, 1)
  float* out = (float*)d_out;                   // (64, 512)

  char* ws = (char*)d_ws;
  float* Qp = (float*)ws;                                // 131072 B
  unsigned short* Wtp = (unsigned short*)(ws + 131072);  // 524288 B
  float* Pstat = (float*)(ws + 131072 + 524288);         // 16384 B (2048 x 2)
  float* Pctx = (float*)(ws + 131072 + 524288 + 16384);  // 4 MB (2048 x 512)

  prep_k<<<256, 256, 0, stream>>>(query, W1, W2, Qp, Wtp);
  scorectx_k<<<2048, 512, 0, stream>>>(values, Wtp, Qp, V1, Pstat, Pctx);
  comb_k<<<64, 512, 0, stream>>>(Pstat, Pctx, out);
}